// Round 15
// baseline (109.869 us; speedup 1.0000x reference)
//
#include <hip/hip_runtime.h>
#include <hip/hip_bf16.h>
#include <math.h>

// Problem constants
#define NB     128          // batches
#define SLEN   4096
#define HID_   1024
#define INDIM_ 272
#define KPAD_  320          // 272 padded to 5*64
#define MFULL  32768
#define N_     1024

typedef __bf16 bf16x8 __attribute__((ext_vector_type(8)));
typedef float  f32x4  __attribute__((ext_vector_type(4)));
typedef float  f32x2  __attribute__((ext_vector_type(2)));
typedef __hip_bfloat16 hb;

// ---------------------------------------------------------------- prep ----

// kt<5: W1 (272x1024) f32 -> w1t (1024x320) bf16^T zero-padded
// kt>=5: W2 (1024x1024) f32 -> w2t (1024x1024) bf16^T
__global__ void prep_w(const float* __restrict__ W1, const float* __restrict__ W2,
                       hb* __restrict__ w1t, hb* __restrict__ w2t) {
    __shared__ float tt[64][65];
    const int kt = blockIdx.x;           // 0..20
    const int nt = blockIdx.y;           // 0..15
    const int c = threadIdx.x & 63, r4 = threadIdx.x >> 6;
    if (kt < 5) {
#pragma unroll
        for (int j = 0; j < 16; ++j) {
            int r = j * 4 + r4;
            int k = kt * 64 + r;
            tt[r][c] = (k < INDIM_) ? W1[k * 1024 + nt * 64 + c] : 0.0f;
        }
        __syncthreads();
#pragma unroll
        for (int j = 0; j < 16; ++j) {
            int r = j * 4 + r4;
            w1t[(nt * 64 + r) * KPAD_ + kt * 64 + c] = __float2bfloat16(tt[c][r]);
        }
    } else {
        const int kw = kt - 5;
#pragma unroll
        for (int j = 0; j < 16; ++j) {
            int r = j * 4 + r4;
            tt[r][c] = W2[(kw * 64 + r) * 1024 + nt * 64 + c];
        }
        __syncthreads();
#pragma unroll
        for (int j = 0; j < 16; ++j) {
            int r = j * 4 + r4;
            w2t[(nt * 64 + r) * 1024 + kw * 64 + c] = __float2bfloat16(tt[c][r]);
        }
    }
}

// Per-(batch, chunk-of-64-patches): np scan (redundant), n_patch output + Mc
// (block 0,0), rowmap + compact feat rows for this chunk, fused balanced
// zero-fill stripe of invalid out rows.
__global__ __launch_bounds__(512) void build_feat_c(const float* __restrict__ x,
                                                    const int* __restrict__ lengths,
                                                    const float* __restrict__ pos_table,
                                                    hb* __restrict__ feat,
                                                    unsigned short* __restrict__ rowmap,
                                                    int* __restrict__ mc,
                                                    float* __restrict__ np_out,
                                                    float* __restrict__ out) {
    __shared__ int scan[NB];
    const int b = blockIdx.x, t = threadIdx.x;
    const int chunk = blockIdx.y;             // 0..3
    if (t < NB) scan[t] = (lengths[t] + 15) >> 4;
    __syncthreads();
    for (int d = 1; d < NB; d <<= 1) {        // Hillis-Steele inclusive scan
        int v = 0;
        if (t < NB && t >= d) v = scan[t - d];
        __syncthreads();
        if (t < NB && t >= d) scan[t] += v;
        __syncthreads();
    }
    const int L = lengths[b];
    const int np = (L + 15) >> 4;
    const int off = scan[b] - np;
    if (b == 0 && chunk == 0) {
        if (t < NB) np_out[t] = (float)((lengths[t] + 15) >> 4);
        if (t == 0) *mc = scan[NB - 1];
    }

    // balanced zero-fill stripe (same distribution as R7's standalone kernel)
    const int z = b * 4 + chunk;              // 0..511
    for (int r = z; r < MFULL; r += 512) {
        const int bb = r >> 8, p = r & 255;
        const int npb = (lengths[bb] + 15) >> 4;
        if (p >= npb)
            *(f32x2*)(out + (long)r * N_ + t * 2) = (f32x2)0.0f;
    }

    const int p0 = chunk * 64;
    const int p1 = min(np, p0 + 64);
    if (p0 >= p1) return;
    const int cnt = p1 - p0;

    for (int p = p0 + t; p < p1; p += 512)
        rowmap[off + p] = (unsigned short)(b * 256 + p);

    const float* xb = x + (long)b * SLEN * 2;
    const int total = cnt * 40;
    for (int c = t; c < total; c += 512) {
        const int pr = c / 40;
        const int p = p0 + pr;
        const int j = c - pr * 40;
        const int col = j * 8;
        bf16x8 v;
        if (j < 2) {
#pragma unroll
            for (int e = 0; e < 8; ++e) {
                int tt2 = p * 16 + j * 8 + e;
                int idx = (tt2 < L) ? tt2 : (L - 1);
                v[e] = (__bf16)xb[(long)idx * 2];
            }
        } else if (col < INDIM_) {
            const int q = col - 16;
            const int tt2 = p * 16 + (q >> 4);
            const int pt = (tt2 < L) ? tt2 : SLEN;
            const float* src = pos_table + pt * 16 + (q & 15);
#pragma unroll
            for (int e = 0; e < 8; ++e) v[e] = (__bf16)src[e];
        } else {
            v = (bf16x8)0;
        }
        *(bf16x8*)(feat + (long)(off + p) * KPAD_ + col) = v;
    }
}

// ---------------------------------------------------------------- GEMM ----

__device__ __forceinline__ void gl_lds16(const hb* g, hb* l) {
    __builtin_amdgcn_global_load_lds(
        (const __attribute__((address_space(1))) unsigned int*)g,
        (__attribute__((address_space(3))) unsigned int*)l, 16, 0, 0);
}

__device__ __forceinline__ float gelu_tanh(float v) {
    float u = 1.5957691216f * v * (1.0f + 0.044715f * v * v);
    float e = __expf(u);
    float th = (e - 1.0f) / (e + 1.0f);
    return 0.5f * v * (1.0f + th);
}

// C(Mc x 1024) = A(Mc x K) @ BT(1024 x K)^T, compact rows.
// BM=256, BN=128, BK=64, 8 waves (4M x 2N, wave-tile 64x64), double-buffered
// 96 KiB LDS, gray quadrants, reg-held B, counted vmcnt(6) (R5-lineage loop).
// nActive = ceil(Mc/256)*8 (~520) -> finer makespan quantization than 256^2.
// MODE 0: HOut = bf16(gelu(C+bias)) compact;  MODE 1: FOut[rowmap[r]] = f32(C+bias)
template <int MODE>
__global__ __launch_bounds__(512, 2) void gemm256(const hb* __restrict__ A,
                                                  const hb* __restrict__ BT,
                                                  const float* __restrict__ bias,
                                                  const unsigned short* __restrict__ rowmap,
                                                  const int* __restrict__ mc,
                                                  hb* __restrict__ HOut,
                                                  float* __restrict__ FOut,
                                                  int K, int nt) {
    __shared__ __align__(16) hb As[2][256 * 64];   // 64 KiB
    __shared__ __align__(16) hb Bs[2][128 * 64];   // 32 KiB

    const int Mc = *mc;
    const int activeBm = (Mc + 255) >> 8;
    const int nActive = activeBm * 8;
    const int bid = blockIdx.x;
    if (bid >= nActive) return;
    // bijective chunked XCD swizzle (m204) over the runtime-active grid
    const int q = nActive >> 3, r = nActive & 7;
    const int xcd = bid & 7, idx = bid >> 3;
    const int wg = (xcd < r ? xcd * (q + 1) : r * (q + 1) + (xcd - r) * q) + idx;
    const int bm = wg >> 3;             // bm-major: 8 bn per bm share A-panel on an XCD
    const int bn = wg & 7;

    const int tid = threadIdx.x;
    const int wid = tid >> 6, lane = tid & 63;
    const int wr = wid >> 1, wc = wid & 1;      // 4 x 2 wave grid, wave-tile 64x64
    const int fr = lane & 15, kg = lane >> 4;
    const int swz = (fr & 7) << 4;              // read-side XOR (bytes)

    const long arow0 = (long)bm * 256;
    const int  brow0 = bn * 128;
    const hb* Bbase = BT + (long)brow0 * K;

    // staging: thread -> 16B; pre-swizzled global source, linear LDS dest
    const int srow = tid >> 3;                  // 0..63
    const int sel  = (((tid & 7) << 4) ^ ((srow & 7) << 4)) >> 1;
    const int ldst = tid * 8;

    f32x4 acc[4][4] = {};

    auto stage = [&](int t, int bsel) {
        const int k0 = t << 6;
#pragma unroll
        for (int j = 0; j < 4; ++j) {           // A: 4 sweeps of 64 rows
            long gr = arow0 + j * 64 + srow;
            if (gr >= Mc) gr = Mc - 1;           // clamp tail rows (dup, discarded)
            gl_lds16(A + gr * K + k0 + sel, &As[bsel][j * 4096 + ldst]);
        }
#pragma unroll
        for (int j = 0; j < 2; ++j)             // B: 2 sweeps
            gl_lds16(Bbase + (long)(j * 64 + srow) * K + k0 + sel,
                     &Bs[bsel][j * 4096 + ldst]);
    };

    stage(0, 0);
    stage(1, 1);
    asm volatile("s_waitcnt vmcnt(6)" ::: "memory");
    asm volatile("s_barrier" ::: "memory");

#define LDA_(dst, Ab, half)                                                  \
    _Pragma("unroll") for (int i = 0; i < 2; ++i)                            \
    _Pragma("unroll") for (int ks = 0; ks < 2; ++ks)                         \
        dst[i][ks] = *(const bf16x8*)((Ab) +                                 \
            (wr * 64 + (half) * 32 + i * 16 + fr) * 128 +                    \
            ((ks * 64 + kg * 16) ^ swz));

#define LDB_(Bb, half)                                                       \
    _Pragma("unroll") for (int jn = 0; jn < 2; ++jn)                         \
    _Pragma("unroll") for (int ks = 0; ks < 2; ++ks)                         \
        Bf[half][jn][ks] = *(const bf16x8*)((Bb) +                           \
            (wc * 64 + (half) * 32 + jn * 16 + fr) * 128 +                   \
            ((ks * 64 + kg * 16) ^ swz));

#define MFMA_QUAD(Aarr, a, b)                                                \
    __builtin_amdgcn_s_setprio(1);                                           \
    _Pragma("unroll") for (int ks = 0; ks < 2; ++ks)                         \
    _Pragma("unroll") for (int i = 0; i < 2; ++i)                            \
    _Pragma("unroll") for (int jn = 0; jn < 2; ++jn)                         \
        acc[(a) * 2 + i][(b) * 2 + jn] =                                     \
            __builtin_amdgcn_mfma_f32_16x16x32_bf16(                         \
                Aarr[i][ks], Bf[b][jn][ks], acc[(a) * 2 + i][(b) * 2 + jn],  \
                0, 0, 0);                                                    \
    __builtin_amdgcn_s_setprio(0);

    for (int t = 0; t < nt; ++t) {
        const char* Ab = (const char*)(&As[t & 1][0]);
        const char* Bb = (const char*)(&Bs[t & 1][0]);
        bf16x8 A0[2][2], A1[2][2], Bf[2][2][2];

        LDB_(Bb, 0)
        LDA_(A0, Ab, 0)
        MFMA_QUAD(A0, 0, 0)
        LDB_(Bb, 1)
        MFMA_QUAD(A0, 0, 1)
        LDA_(A1, Ab, 1)
        MFMA_QUAD(A1, 1, 1)
        asm volatile("s_waitcnt lgkmcnt(0)" ::: "memory");
        asm volatile("s_barrier" ::: "memory");
        if (t + 2 < nt) stage(t + 2, t & 1);
        MFMA_QUAD(A1, 1, 0)
        if (t + 1 < nt) {
            if (t + 2 < nt) {
                asm volatile("s_waitcnt vmcnt(6)" ::: "memory");
            } else {
                asm volatile("s_waitcnt vmcnt(0)" ::: "memory");
            }
            asm volatile("s_barrier" ::: "memory");
        }
    }

    // ---- LDS-staged epilogue ----
    const int rbase = wr * 64 + kg * 4;        // row base within 256
    const int cbase = wc * 64 + fr;            // col base within 128
    float bvv[4];
#pragma unroll
    for (int ni = 0; ni < 4; ++ni) bvv[ni] = bias[bn * 128 + cbase + ni * 16];

    if (MODE == 0) {
        hb* Cs = (hb*)As;                      // 256 x 128 bf16 tile (64 KiB)
#pragma unroll
        for (int ni = 0; ni < 4; ++ni) {
            const int col = cbase + ni * 16;
#pragma unroll
            for (int mi = 0; mi < 4; ++mi)
#pragma unroll
                for (int r2 = 0; r2 < 4; ++r2) {
                    float v = acc[mi][ni][r2] + bvv[ni];
                    Cs[(rbase + mi * 16 + r2) * 128 + col] = __float2bfloat16(gelu_tanh(v));
                }
        }
        __syncthreads();
        const hb* Cl = (const hb*)As;
#pragma unroll
        for (int c = 0; c < 8; ++c) {
            const int e = (c * 512 + tid) * 8;
            const int row = e >> 7, col = e & 127;
            bf16x8 v = *(const bf16x8*)(Cl + e);
            *(bf16x8*)(HOut + (arow0 + row) * N_ + bn * 128 + col) = v;
        }
    } else {
        float* Cf = (float*)As;                // 128 x 128 f32 per row-half (64 KiB)
#pragma unroll
        for (int half = 0; half < 2; ++half) {
            if (half) __syncthreads();
            if ((wr >> 1) == half) {
#pragma unroll
                for (int ni = 0; ni < 4; ++ni) {
                    const int col = cbase + ni * 16;
#pragma unroll
                    for (int mi = 0; mi < 4; ++mi)
#pragma unroll
                        for (int r2 = 0; r2 < 4; ++r2) {
                            const int row = (wr & 1) * 64 + mi * 16 + kg * 4 + r2;
                            Cf[row * 128 + col] = acc[mi][ni][r2] + bvv[ni];
                        }
                }
            }
            __syncthreads();
#pragma unroll
            for (int c = 0; c < 8; ++c) {
                const int e = (c * 512 + tid) * 4;
                const int row = e >> 7, col = e & 127;
                const long cidx = arow0 + half * 128 + row;
                if (cidx < Mc) {
                    f32x4 v = *(const f32x4*)(Cf + e);
                    *(f32x4*)(FOut + (long)rowmap[cidx] * N_ + bn * 128 + col) = v;
                }
            }
        }
    }
}

// -------------------------------------------------------------- launch ----

extern "C" void kernel_launch(void* const* d_in, const int* in_sizes, int n_in,
                              void* d_out, int out_size, void* d_ws, size_t ws_size,
                              hipStream_t stream) {
    const float* x         = (const float*)d_in[0];
    const int*   lengths   = (const int*)d_in[1];
    const float* pos_table = (const float*)d_in[2];
    const float* W1        = (const float*)d_in[3];
    const float* b1        = (const float*)d_in[4];
    const float* W2        = (const float*)d_in[5];
    const float* b2        = (const float*)d_in[6];
    float* out = (float*)d_out;

    char* ws = (char*)d_ws;
    hb* w1t                = (hb*)(ws);                        //    655,360 B
    hb* w2t                = (hb*)(ws + 655360);               //  2,097,152 B
    hb* feat               = (hb*)(ws + 2752512);              // 20,971,520 B max
    hb* h                  = (hb*)(ws + 23724032);             // 67,108,864 B max
    unsigned short* rowmap = (unsigned short*)(ws + 90832896); //     65,536 B
    int* mc                = (int*)(ws + 90898432);            //          4 B

    hipLaunchKernelGGL(prep_w, dim3(21, 16), dim3(256), 0, stream, W1, W2, w1t, w2t);
    hipLaunchKernelGGL(build_feat_c, dim3(NB, 4), dim3(512), 0, stream,
                       x, lengths, pos_table, feat, rowmap, mc,
                       out + (long)MFULL * N_, out);

    // gemm grids: nActive = ceil(Mc/256)*8 <= 1024; excess blocks exit immediately
    hipLaunchKernelGGL((gemm256<0>), dim3(1024), dim3(512), 0, stream,
                       feat, w1t, b1, rowmap, mc, h, nullptr, KPAD_, KPAD_ / 64);
    hipLaunchKernelGGL((gemm256<1>), dim3(1024), dim3(512), 0, stream,
                       h, w2t, b2, rowmap, mc, nullptr, out, HID_, HID_ / 64);
}

// Round 16
// 96.525 us; speedup vs baseline: 1.1382x; 1.1382x over previous
//
#include <hip/hip_runtime.h>
#include <hip/hip_bf16.h>
#include <math.h>

// Problem constants
#define NB     128          // batches
#define SLEN   4096
#define HID_   1024
#define INDIM_ 272
#define KPAD_  320          // 272 padded to 5*64
#define MFULL  32768
#define N_     1024

typedef __bf16 bf16x8 __attribute__((ext_vector_type(8)));
typedef float  f32x4  __attribute__((ext_vector_type(4)));
typedef float  f32x2  __attribute__((ext_vector_type(2)));
typedef __hip_bfloat16 hb;

// ---------------------------------------------------------------- prep ----

// kt<5: W1 (272x1024) f32 -> w1t (1024x320) bf16^T zero-padded
// kt>=5: W2 (1024x1024) f32 -> w2t (1024x1024) bf16^T
__global__ void prep_w(const float* __restrict__ W1, const float* __restrict__ W2,
                       hb* __restrict__ w1t, hb* __restrict__ w2t) {
    __shared__ float tt[64][65];
    const int kt = blockIdx.x;           // 0..20
    const int nt = blockIdx.y;           // 0..15
    const int c = threadIdx.x & 63, r4 = threadIdx.x >> 6;
    if (kt < 5) {
#pragma unroll
        for (int j = 0; j < 16; ++j) {
            int r = j * 4 + r4;
            int k = kt * 64 + r;
            tt[r][c] = (k < INDIM_) ? W1[k * 1024 + nt * 64 + c] : 0.0f;
        }
        __syncthreads();
#pragma unroll
        for (int j = 0; j < 16; ++j) {
            int r = j * 4 + r4;
            w1t[(nt * 64 + r) * KPAD_ + kt * 64 + c] = __float2bfloat16(tt[c][r]);
        }
    } else {
        const int kw = kt - 5;
#pragma unroll
        for (int j = 0; j < 16; ++j) {
            int r = j * 4 + r4;
            tt[r][c] = W2[(kw * 64 + r) * 1024 + nt * 64 + c];
        }
        __syncthreads();
#pragma unroll
        for (int j = 0; j < 16; ++j) {
            int r = j * 4 + r4;
            w2t[(nt * 64 + r) * 1024 + kw * 64 + c] = __float2bfloat16(tt[c][r]);
        }
    }
}

// Per-(batch, chunk-of-64-patches): np scan (redundant), n_patch output + Mc
// (block 0,0), rowmap + compact feat rows for this chunk, fused balanced
// zero-fill stripe of invalid out rows.
__global__ __launch_bounds__(512) void build_feat_c(const float* __restrict__ x,
                                                    const int* __restrict__ lengths,
                                                    const float* __restrict__ pos_table,
                                                    hb* __restrict__ feat,
                                                    unsigned short* __restrict__ rowmap,
                                                    int* __restrict__ mc,
                                                    float* __restrict__ np_out,
                                                    float* __restrict__ out) {
    __shared__ int scan[NB];
    const int b = blockIdx.x, t = threadIdx.x;
    const int chunk = blockIdx.y;             // 0..3
    if (t < NB) scan[t] = (lengths[t] + 15) >> 4;
    __syncthreads();
    for (int d = 1; d < NB; d <<= 1) {        // Hillis-Steele inclusive scan
        int v = 0;
        if (t < NB && t >= d) v = scan[t - d];
        __syncthreads();
        if (t < NB && t >= d) scan[t] += v;
        __syncthreads();
    }
    const int L = lengths[b];
    const int np = (L + 15) >> 4;
    const int off = scan[b] - np;
    if (b == 0 && chunk == 0) {
        if (t < NB) np_out[t] = (float)((lengths[t] + 15) >> 4);
        if (t == 0) *mc = scan[NB - 1];
    }

    // balanced zero-fill stripe (same distribution as R7's standalone kernel)
    const int z = b * 4 + chunk;              // 0..511
    for (int r = z; r < MFULL; r += 512) {
        const int bb = r >> 8, p = r & 255;
        const int npb = (lengths[bb] + 15) >> 4;
        if (p >= npb)
            *(f32x2*)(out + (long)r * N_ + t * 2) = (f32x2)0.0f;
    }

    const int p0 = chunk * 64;
    const int p1 = min(np, p0 + 64);
    if (p0 >= p1) return;
    const int cnt = p1 - p0;

    for (int p = p0 + t; p < p1; p += 512)
        rowmap[off + p] = (unsigned short)(b * 256 + p);

    const float* xb = x + (long)b * SLEN * 2;
    const int total = cnt * 40;
    for (int c = t; c < total; c += 512) {
        const int pr = c / 40;
        const int p = p0 + pr;
        const int j = c - pr * 40;
        const int col = j * 8;
        bf16x8 v;
        if (j < 2) {
#pragma unroll
            for (int e = 0; e < 8; ++e) {
                int tt2 = p * 16 + j * 8 + e;
                int idx = (tt2 < L) ? tt2 : (L - 1);
                v[e] = (__bf16)xb[(long)idx * 2];
            }
        } else if (col < INDIM_) {
            const int q = col - 16;
            const int tt2 = p * 16 + (q >> 4);
            const int pt = (tt2 < L) ? tt2 : SLEN;
            const float* src = pos_table + pt * 16 + (q & 15);
#pragma unroll
            for (int e = 0; e < 8; ++e) v[e] = (__bf16)src[e];
        } else {
            v = (bf16x8)0;
        }
        *(bf16x8*)(feat + (long)(off + p) * KPAD_ + col) = v;
    }
}

// ---------------------------------------------------------------- GEMM ----

__device__ __forceinline__ void gl_lds16(const hb* g, hb* l) {
    __builtin_amdgcn_global_load_lds(
        (const __attribute__((address_space(1))) unsigned int*)g,
        (__attribute__((address_space(3))) unsigned int*)l, 16, 0, 0);
}

__device__ __forceinline__ float gelu_tanh(float v) {
    float u = 1.5957691216f * v * (1.0f + 0.044715f * v * v);
    float e = __expf(u);
    float th = (e - 1.0f) / (e + 1.0f);
    return 0.5f * v * (1.0f + th);
}

// C(Mc x 1024) = A(Mc x K) @ BT(1024 x K)^T, compact rows.
// 256x256 tile, BK=64, 8 waves (2x4), double-buffered LDS (R5/R7-proven loop).
// Runtime-bijective XCD swizzle over nActive = ceil(Mc/256)*4 blocks.
// MODE 0: HOut = bf16(gelu(C+bias)) compact (LDS-staged stores).
// MODE 1: FOut[rowmap[r]] = f32(C+bias) via DIRECT 64-B-aligned scatter stores.
template <int MODE>
__global__ __launch_bounds__(512, 2) void gemm256(const hb* __restrict__ A,
                                                  const hb* __restrict__ BT,
                                                  const float* __restrict__ bias,
                                                  const unsigned short* __restrict__ rowmap,
                                                  const int* __restrict__ mc,
                                                  hb* __restrict__ HOut,
                                                  float* __restrict__ FOut,
                                                  int K, int nt) {
    __shared__ __align__(16) hb Sh[4][16384];   // A: Sh[0..1], B: Sh[2..3]; 128 KiB

    const int Mc = *mc;
    const int activeBm = (Mc + 255) >> 8;
    const int nActive = activeBm * 4;
    const int bid = blockIdx.x;
    if (bid >= nActive) return;
    // bijective chunked XCD swizzle (m204) over the runtime-active grid
    const int q = nActive >> 3, r = nActive & 7;
    const int xcd = bid & 7, idx = bid >> 3;
    const int wg = (xcd < r ? xcd * (q + 1) : r * (q + 1) + (xcd - r) * q) + idx;
    const int bm = wg >> 2;             // bm-major: 4 bn per bm share A-panel on an XCD
    const int bn = wg & 3;

    const int tid = threadIdx.x;
    const int wid = tid >> 6, lane = tid & 63;
    const int wr = wid >> 2, wc = wid & 3;      // 2 x 4 wave grid
    const int fr = lane & 15, kg = lane >> 4;
    const int swz = (fr & 7) << 4;              // read-side XOR (bytes)

    const long arow0 = (long)bm * 256;
    const int  brow0 = bn * 256;
    const hb* Bbase = BT + (long)brow0 * K;

    // staging: thread -> 16B; pre-swizzled global source, linear LDS dest
    const int srow = tid >> 3;
    const int sel  = (((tid & 7) << 4) ^ ((srow & 7) << 4)) >> 1;
    const int ldst = tid * 8;

    f32x4 acc[8][4] = {};

    auto stage = [&](int t, int bsel) {
        const int k0 = t << 6;
#pragma unroll
        for (int j = 0; j < 4; ++j) {
            long gr = arow0 + j * 64 + srow;
            if (gr >= Mc) gr = Mc - 1;           // clamp tail rows (dup, discarded)
            gl_lds16(A + gr * K + k0 + sel, &Sh[bsel][j * 4096 + ldst]);
        }
#pragma unroll
        for (int j = 0; j < 4; ++j)
            gl_lds16(Bbase + (long)(j * 64 + srow) * K + k0 + sel,
                     &Sh[2 + bsel][j * 4096 + ldst]);
    };

    stage(0, 0);
    stage(1, 1);
    asm volatile("s_waitcnt vmcnt(8)" ::: "memory");
    asm volatile("s_barrier" ::: "memory");

#define LDA_(dst, Ab, half)                                                  \
    _Pragma("unroll") for (int i = 0; i < 4; ++i)                            \
    _Pragma("unroll") for (int ks = 0; ks < 2; ++ks)                         \
        dst[i][ks] = *(const bf16x8*)((Ab) +                                 \
            (wr * 128 + (half) * 64 + i * 16 + fr) * 128 +                   \
            ((ks * 64 + kg * 16) ^ swz));

#define LDB_(Bb, half)                                                       \
    _Pragma("unroll") for (int jn = 0; jn < 2; ++jn)                         \
    _Pragma("unroll") for (int ks = 0; ks < 2; ++ks)                         \
        Bf[half][jn][ks] = *(const bf16x8*)((Bb) +                           \
            (wc * 64 + (half) * 32 + jn * 16 + fr) * 128 +                   \
            ((ks * 64 + kg * 16) ^ swz));

#define MFMA_QUAD(Aarr, a, b)                                                \
    __builtin_amdgcn_s_setprio(1);                                           \
    _Pragma("unroll") for (int ks = 0; ks < 2; ++ks)                         \
    _Pragma("unroll") for (int i = 0; i < 4; ++i)                            \
    _Pragma("unroll") for (int jn = 0; jn < 2; ++jn)                         \
        acc[(a) * 4 + i][(b) * 2 + jn] =                                     \
            __builtin_amdgcn_mfma_f32_16x16x32_bf16(                         \
                Aarr[i][ks], Bf[b][jn][ks], acc[(a) * 4 + i][(b) * 2 + jn],  \
                0, 0, 0);                                                    \
    __builtin_amdgcn_s_setprio(0);

    for (int t = 0; t < nt; ++t) {
        const char* Ab = (const char*)(&Sh[t & 1][0]);
        const char* Bb = (const char*)(&Sh[2 + (t & 1)][0]);
        bf16x8 A0[4][2], A1[4][2], Bf[2][2][2];

        LDB_(Bb, 0)
        LDA_(A0, Ab, 0)
        MFMA_QUAD(A0, 0, 0)
        LDB_(Bb, 1)
        MFMA_QUAD(A0, 0, 1)
        LDA_(A1, Ab, 1)
        MFMA_QUAD(A1, 1, 1)
        asm volatile("s_waitcnt lgkmcnt(0)" ::: "memory");
        asm volatile("s_barrier" ::: "memory");
        if (t + 2 < nt) stage(t + 2, t & 1);
        MFMA_QUAD(A1, 1, 0)
        if (t + 1 < nt) {
            if (t + 2 < nt) {
                asm volatile("s_waitcnt vmcnt(8)" ::: "memory");
            } else {
                asm volatile("s_waitcnt vmcnt(0)" ::: "memory");
            }
            asm volatile("s_barrier" ::: "memory");
        }
    }

    // ---- epilogue ----
    const int rbase = wr * 128 + kg * 4;
    const int cbase = wc * 64 + fr;
    float bvv[4];
#pragma unroll
    for (int ni = 0; ni < 4; ++ni) bvv[ni] = bias[bn * 256 + cbase + ni * 16];

    if (MODE == 0) {
        // LDS-staged (essential for bf16: direct 2-B scatter would shred sectors)
        hb* Cs = (hb*)Sh;                      // 256 x 256 bf16 tile
#pragma unroll
        for (int ni = 0; ni < 4; ++ni) {
            const int col = cbase + ni * 16;
#pragma unroll
            for (int mi = 0; mi < 8; ++mi)
#pragma unroll
                for (int r2 = 0; r2 < 4; ++r2) {
                    float v = acc[mi][ni][r2] + bvv[ni];
                    Cs[(rbase + mi * 16 + r2) * 256 + col] = __float2bfloat16(gelu_tanh(v));
                }
        }
        __syncthreads();
        const hb* Cl = (const hb*)Sh;
#pragma unroll
        for (int c = 0; c < 16; ++c) {
            const int e = (c * 512 + tid) * 8;
            const int row = e >> 8, col = e & 255;
            bf16x8 v = *(const bf16x8*)(Cl + e);
            *(bf16x8*)(HOut + (arow0 + row) * N_ + bn * 256 + col) = v;
        }
    } else {
        // direct scatter: each store = 4 rows x 64-B aligned runs, amp 1.0
#pragma unroll
        for (int mi = 0; mi < 8; ++mi) {
#pragma unroll
            for (int r2 = 0; r2 < 4; ++r2) {
                const long cidx = arow0 + rbase + mi * 16 + r2;
                if (cidx < Mc) {
                    float* orow = FOut + (long)rowmap[cidx] * N_ + bn * 256;
#pragma unroll
                    for (int ni = 0; ni < 4; ++ni)
                        orow[cbase + ni * 16] = acc[mi][ni][r2] + bvv[ni];
                }
            }
        }
    }
}

// -------------------------------------------------------------- launch ----

extern "C" void kernel_launch(void* const* d_in, const int* in_sizes, int n_in,
                              void* d_out, int out_size, void* d_ws, size_t ws_size,
                              hipStream_t stream) {
    const float* x         = (const float*)d_in[0];
    const int*   lengths   = (const int*)d_in[1];
    const float* pos_table = (const float*)d_in[2];
    const float* W1        = (const float*)d_in[3];
    const float* b1        = (const float*)d_in[4];
    const float* W2        = (const float*)d_in[5];
    const float* b2        = (const float*)d_in[6];
    float* out = (float*)d_out;

    char* ws = (char*)d_ws;
    hb* w1t                = (hb*)(ws);                        //    655,360 B
    hb* w2t                = (hb*)(ws + 655360);               //  2,097,152 B
    hb* feat               = (hb*)(ws + 2752512);              // 20,971,520 B max
    hb* h                  = (hb*)(ws + 23724032);             // 67,108,864 B max
    unsigned short* rowmap = (unsigned short*)(ws + 90832896); //     65,536 B
    int* mc                = (int*)(ws + 90898432);            //          4 B

    hipLaunchKernelGGL(prep_w, dim3(21, 16), dim3(256), 0, stream, W1, W2, w1t, w2t);
    hipLaunchKernelGGL(build_feat_c, dim3(NB, 4), dim3(512), 0, stream,
                       x, lengths, pos_table, feat, rowmap, mc,
                       out + (long)MFULL * N_, out);

    // gemm grids: nActive <= 272; excess blocks exit immediately
    hipLaunchKernelGGL((gemm256<0>), dim3(512), dim3(512), 0, stream,
                       feat, w1t, b1, rowmap, mc, h, nullptr, KPAD_, KPAD_ / 64);
    hipLaunchKernelGGL((gemm256<1>), dim3(512), dim3(512), 0, stream,
                       h, w2t, b2, rowmap, mc, nullptr, out, HID_, HID_ / 64);
}

// Round 17
// 90.161 us; speedup vs baseline: 1.2186x; 1.0706x over previous
//
#include <hip/hip_runtime.h>
#include <hip/hip_bf16.h>
#include <math.h>

// Problem constants
#define NB     128          // batches
#define SLEN   4096
#define HID_   1024
#define INDIM_ 272
#define KPAD_  320          // 272 padded to 5*64
#define MFULL  32768
#define N_     1024

typedef __bf16 bf16x8 __attribute__((ext_vector_type(8)));
typedef float  f32x4  __attribute__((ext_vector_type(4)));
typedef float  f32x2  __attribute__((ext_vector_type(2)));
typedef __hip_bfloat16 hb;

// ---------------------------------------------------------------- prep ----
// Fused prep + feat kernel, 512 threads/block:
//  bid <  336           : weight transposes (kt = bid/16: <5 -> w1t, else w2t)
//  bid in [336, 336+512): per-(batch, chunk-of-64-patches) feat build + scan +
//                         rowmap + Mc/n_patch + balanced zero-fill stripe.
__global__ __launch_bounds__(512) void prep_and_feat(const float* __restrict__ x,
                                                     const int* __restrict__ lengths,
                                                     const float* __restrict__ pos_table,
                                                     const float* __restrict__ W1,
                                                     const float* __restrict__ W2,
                                                     hb* __restrict__ w1t,
                                                     hb* __restrict__ w2t,
                                                     hb* __restrict__ feat,
                                                     unsigned short* __restrict__ rowmap,
                                                     int* __restrict__ mc,
                                                     float* __restrict__ np_out,
                                                     float* __restrict__ out) {
    const int bid = blockIdx.x;
    const int t = threadIdx.x;

    if (bid < 336) {
        // ---- weight transposes (64x64 f32 tile via LDS) ----
        __shared__ float tt[64][65];
        const int kt = bid >> 4;             // 0..20
        const int nt = bid & 15;             // 0..15
        const int c = t & 63, r8 = t >> 6;   // r8: 0..7
        if (kt < 5) {
#pragma unroll
            for (int j = 0; j < 8; ++j) {
                int r = j * 8 + r8;
                int k = kt * 64 + r;
                tt[r][c] = (k < INDIM_) ? W1[k * 1024 + nt * 64 + c] : 0.0f;
            }
            __syncthreads();
#pragma unroll
            for (int j = 0; j < 8; ++j) {
                int r = j * 8 + r8;
                w1t[(nt * 64 + r) * KPAD_ + kt * 64 + c] = __float2bfloat16(tt[c][r]);
            }
        } else {
            const int kw = kt - 5;
#pragma unroll
            for (int j = 0; j < 8; ++j) {
                int r = j * 8 + r8;
                tt[r][c] = W2[(kw * 64 + r) * 1024 + nt * 64 + c];
            }
            __syncthreads();
#pragma unroll
            for (int j = 0; j < 8; ++j) {
                int r = j * 8 + r8;
                w2t[(nt * 64 + r) * 1024 + kw * 64 + c] = __float2bfloat16(tt[c][r]);
            }
        }
        return;
    }

    // ---- feat build branch ----
    __shared__ int scan[NB];
    const int fid = bid - 336;                // 0..511
    const int b = fid >> 2;                   // batch
    const int chunk = fid & 3;                // 0..3
    if (t < NB) scan[t] = (lengths[t] + 15) >> 4;
    __syncthreads();
    for (int d = 1; d < NB; d <<= 1) {        // Hillis-Steele inclusive scan
        int v = 0;
        if (t < NB && t >= d) v = scan[t - d];
        __syncthreads();
        if (t < NB && t >= d) scan[t] += v;
        __syncthreads();
    }
    const int L = lengths[b];
    const int np = (L + 15) >> 4;
    const int off = scan[b] - np;
    if (b == 0 && chunk == 0) {
        if (t < NB) np_out[t] = (float)((lengths[t] + 15) >> 4);
        if (t == 0) *mc = scan[NB - 1];
    }

    // balanced zero-fill stripe (same distribution as R7's standalone kernel)
    const int z = b * 4 + chunk;              // 0..511
    for (int r = z; r < MFULL; r += 512) {
        const int bb = r >> 8, p = r & 255;
        const int npb = (lengths[bb] + 15) >> 4;
        if (p >= npb)
            *(f32x2*)(out + (long)r * N_ + t * 2) = (f32x2)0.0f;
    }

    const int p0 = chunk * 64;
    const int p1 = min(np, p0 + 64);
    if (p0 >= p1) return;
    const int cnt = p1 - p0;

    for (int p = p0 + t; p < p1; p += 512)
        rowmap[off + p] = (unsigned short)(b * 256 + p);

    const float* xb = x + (long)b * SLEN * 2;
    const int total = cnt * 40;
    for (int c = t; c < total; c += 512) {
        const int pr = c / 40;
        const int p = p0 + pr;
        const int j = c - pr * 40;
        const int col = j * 8;
        bf16x8 v;
        if (j < 2) {
#pragma unroll
            for (int e = 0; e < 8; ++e) {
                int tt2 = p * 16 + j * 8 + e;
                int idx = (tt2 < L) ? tt2 : (L - 1);
                v[e] = (__bf16)xb[(long)idx * 2];
            }
        } else if (col < INDIM_) {
            const int q = col - 16;
            const int tt2 = p * 16 + (q >> 4);
            const int pt = (tt2 < L) ? tt2 : SLEN;
            const float* src = pos_table + pt * 16 + (q & 15);
#pragma unroll
            for (int e = 0; e < 8; ++e) v[e] = (__bf16)src[e];
        } else {
            v = (bf16x8)0;
        }
        *(bf16x8*)(feat + (long)(off + p) * KPAD_ + col) = v;
    }
}

// ---------------------------------------------------------------- GEMM ----

__device__ __forceinline__ void gl_lds16(const hb* g, hb* l) {
    __builtin_amdgcn_global_load_lds(
        (const __attribute__((address_space(1))) unsigned int*)g,
        (__attribute__((address_space(3))) unsigned int*)l, 16, 0, 0);
}

__device__ __forceinline__ float gelu_tanh(float v) {
    float u = 1.5957691216f * v * (1.0f + 0.044715f * v * v);
    float e = __expf(u);
    float th = (e - 1.0f) / (e + 1.0f);
    return 0.5f * v * (1.0f + th);
}

// C(Mc x 1024) = A(Mc x K) @ BT(1024 x K)^T, compact rows.
// 256x256 tile, BK=64, 8 waves (2x4), double-buffered LDS (R5/R7-proven loop).
// Runtime-bijective XCD swizzle over nActive = ceil(Mc/256)*4 blocks.
// MODE 0: HOut = bf16(gelu(C+bias)) compact (LDS-staged stores).
// MODE 1: FOut[rowmap[r]] = f32(C+bias) via DIRECT 64-B-aligned scatter stores.
template <int MODE>
__global__ __launch_bounds__(512, 2) void gemm256(const hb* __restrict__ A,
                                                  const hb* __restrict__ BT,
                                                  const float* __restrict__ bias,
                                                  const unsigned short* __restrict__ rowmap,
                                                  const int* __restrict__ mc,
                                                  hb* __restrict__ HOut,
                                                  float* __restrict__ FOut,
                                                  int K, int nt) {
    __shared__ __align__(16) hb Sh[4][16384];   // A: Sh[0..1], B: Sh[2..3]; 128 KiB

    const int Mc = *mc;
    const int activeBm = (Mc + 255) >> 8;
    const int nActive = activeBm * 4;
    const int bid = blockIdx.x;
    if (bid >= nActive) return;
    // bijective chunked XCD swizzle (m204) over the runtime-active grid
    const int q = nActive >> 3, r = nActive & 7;
    const int xcd = bid & 7, idx = bid >> 3;
    const int wg = (xcd < r ? xcd * (q + 1) : r * (q + 1) + (xcd - r) * q) + idx;
    const int bm = wg >> 2;             // bm-major: 4 bn per bm share A-panel on an XCD
    const int bn = wg & 3;

    const int tid = threadIdx.x;
    const int wid = tid >> 6, lane = tid & 63;
    const int wr = wid >> 2, wc = wid & 3;      // 2 x 4 wave grid
    const int fr = lane & 15, kg = lane >> 4;
    const int swz = (fr & 7) << 4;              // read-side XOR (bytes)

    const long arow0 = (long)bm * 256;
    const int  brow0 = bn * 256;
    const hb* Bbase = BT + (long)brow0 * K;

    // staging: thread -> 16B; pre-swizzled global source, linear LDS dest
    const int srow = tid >> 3;
    const int sel  = (((tid & 7) << 4) ^ ((srow & 7) << 4)) >> 1;
    const int ldst = tid * 8;

    f32x4 acc[8][4] = {};

    auto stage = [&](int t, int bsel) {
        const int k0 = t << 6;
#pragma unroll
        for (int j = 0; j < 4; ++j) {
            long gr = arow0 + j * 64 + srow;
            if (gr >= Mc) gr = Mc - 1;           // clamp tail rows (dup, discarded)
            gl_lds16(A + gr * K + k0 + sel, &Sh[bsel][j * 4096 + ldst]);
        }
#pragma unroll
        for (int j = 0; j < 4; ++j)
            gl_lds16(Bbase + (long)(j * 64 + srow) * K + k0 + sel,
                     &Sh[2 + bsel][j * 4096 + ldst]);
    };

    stage(0, 0);
    stage(1, 1);
    asm volatile("s_waitcnt vmcnt(8)" ::: "memory");
    asm volatile("s_barrier" ::: "memory");

#define LDA_(dst, Ab, half)                                                  \
    _Pragma("unroll") for (int i = 0; i < 4; ++i)                            \
    _Pragma("unroll") for (int ks = 0; ks < 2; ++ks)                         \
        dst[i][ks] = *(const bf16x8*)((Ab) +                                 \
            (wr * 128 + (half) * 64 + i * 16 + fr) * 128 +                   \
            ((ks * 64 + kg * 16) ^ swz));

#define LDB_(Bb, half)                                                       \
    _Pragma("unroll") for (int jn = 0; jn < 2; ++jn)                         \
    _Pragma("unroll") for (int ks = 0; ks < 2; ++ks)                         \
        Bf[half][jn][ks] = *(const bf16x8*)((Bb) +                           \
            (wc * 64 + (half) * 32 + jn * 16 + fr) * 128 +                   \
            ((ks * 64 + kg * 16) ^ swz));

#define MFMA_QUAD(Aarr, a, b)                                                \
    __builtin_amdgcn_s_setprio(1);                                           \
    _Pragma("unroll") for (int ks = 0; ks < 2; ++ks)                         \
    _Pragma("unroll") for (int i = 0; i < 4; ++i)                            \
    _Pragma("unroll") for (int jn = 0; jn < 2; ++jn)                         \
        acc[(a) * 4 + i][(b) * 2 + jn] =                                     \
            __builtin_amdgcn_mfma_f32_16x16x32_bf16(                         \
                Aarr[i][ks], Bf[b][jn][ks], acc[(a) * 4 + i][(b) * 2 + jn],  \
                0, 0, 0);                                                    \
    __builtin_amdgcn_s_setprio(0);

    for (int t = 0; t < nt; ++t) {
        const char* Ab = (const char*)(&Sh[t & 1][0]);
        const char* Bb = (const char*)(&Sh[2 + (t & 1)][0]);
        bf16x8 A0[4][2], A1[4][2], Bf[2][2][2];

        LDB_(Bb, 0)
        LDA_(A0, Ab, 0)
        MFMA_QUAD(A0, 0, 0)
        LDB_(Bb, 1)
        MFMA_QUAD(A0, 0, 1)
        LDA_(A1, Ab, 1)
        MFMA_QUAD(A1, 1, 1)
        asm volatile("s_waitcnt lgkmcnt(0)" ::: "memory");
        asm volatile("s_barrier" ::: "memory");
        if (t + 2 < nt) stage(t + 2, t & 1);
        MFMA_QUAD(A1, 1, 0)
        if (t + 1 < nt) {
            if (t + 2 < nt) {
                asm volatile("s_waitcnt vmcnt(8)" ::: "memory");
            } else {
                asm volatile("s_waitcnt vmcnt(0)" ::: "memory");
            }
            asm volatile("s_barrier" ::: "memory");
        }
    }

    // ---- epilogue ----
    const int rbase = wr * 128 + kg * 4;
    const int cbase = wc * 64 + fr;
    float bvv[4];
#pragma unroll
    for (int ni = 0; ni < 4; ++ni) bvv[ni] = bias[bn * 256 + cbase + ni * 16];

    if (MODE == 0) {
        // LDS-staged (essential for bf16: direct 2-B scatter would shred sectors)
        hb* Cs = (hb*)Sh;                      // 256 x 256 bf16 tile
#pragma unroll
        for (int ni = 0; ni < 4; ++ni) {
            const int col = cbase + ni * 16;
#pragma unroll
            for (int mi = 0; mi < 8; ++mi)
#pragma unroll
                for (int r2 = 0; r2 < 4; ++r2) {
                    float v = acc[mi][ni][r2] + bvv[ni];
                    Cs[(rbase + mi * 16 + r2) * 256 + col] = __float2bfloat16(gelu_tanh(v));
                }
        }
        __syncthreads();
        const hb* Cl = (const hb*)Sh;
#pragma unroll
        for (int c = 0; c < 16; ++c) {
            const int e = (c * 512 + tid) * 8;
            const int row = e >> 8, col = e & 255;
            bf16x8 v = *(const bf16x8*)(Cl + e);
            *(bf16x8*)(HOut + (arow0 + row) * N_ + bn * 256 + col) = v;
        }
    } else {
        // direct scatter: each store = 4 rows x 64-B aligned runs, amp 1.0
#pragma unroll
        for (int mi = 0; mi < 8; ++mi) {
#pragma unroll
            for (int r2 = 0; r2 < 4; ++r2) {
                const long cidx = arow0 + rbase + mi * 16 + r2;
                if (cidx < Mc) {
                    float* orow = FOut + (long)rowmap[cidx] * N_ + bn * 256;
#pragma unroll
                    for (int ni = 0; ni < 4; ++ni)
                        orow[cbase + ni * 16] = acc[mi][ni][r2] + bvv[ni];
                }
            }
        }
    }
}

// -------------------------------------------------------------- launch ----

extern "C" void kernel_launch(void* const* d_in, const int* in_sizes, int n_in,
                              void* d_out, int out_size, void* d_ws, size_t ws_size,
                              hipStream_t stream) {
    const float* x         = (const float*)d_in[0];
    const int*   lengths   = (const int*)d_in[1];
    const float* pos_table = (const float*)d_in[2];
    const float* W1        = (const float*)d_in[3];
    const float* b1        = (const float*)d_in[4];
    const float* W2        = (const float*)d_in[5];
    const float* b2        = (const float*)d_in[6];
    float* out = (float*)d_out;

    char* ws = (char*)d_ws;
    hb* w1t                = (hb*)(ws);                        //    655,360 B
    hb* w2t                = (hb*)(ws + 655360);               //  2,097,152 B
    hb* feat               = (hb*)(ws + 2752512);              // 20,971,520 B max
    hb* h                  = (hb*)(ws + 23724032);             // 67,108,864 B max
    unsigned short* rowmap = (unsigned short*)(ws + 90832896); //     65,536 B
    int* mc                = (int*)(ws + 90898432);            //          4 B

    hipLaunchKernelGGL(prep_and_feat, dim3(336 + 512), dim3(512), 0, stream,
                       x, lengths, pos_table, W1, W2, w1t, w2t, feat, rowmap, mc,
                       out + (long)MFULL * N_, out);

    // gemm grids: nActive <= 272; excess blocks exit immediately
    hipLaunchKernelGGL((gemm256<0>), dim3(512), dim3(512), 0, stream,
                       feat, w1t, b1, rowmap, mc, h, nullptr, KPAD_, KPAD_ / 64);
    hipLaunchKernelGGL((gemm256<1>), dim3(512), dim3(512), 0, stream,
                       h, w2t, b2, rowmap, mc, nullptr, out, HID_, HID_ / 64);
}